// Round 5
// baseline (335.027 us; speedup 1.0000x reference)
//
#include <hip/hip_runtime.h>
#include <hip/hip_fp16.h>
#include <cmath>

#define BATCH 1024
#define SOUT 36336
#define POUT 10596
#define PS_COLS 10464   // s params compacted (dec2 block removed)
#define PP_COLS 10596
#define PD_COLS 25872   // s dec2 block (W 32x784 + b 784)

__device__ __forceinline__ float sigmoidf_(float x){ return 1.0f/(1.0f+__expf(-x)); }
__device__ __forceinline__ float reluf_(float x){ return x>0.0f?x:0.0f; }

// ---------------- K1: backbone hidden h2 (s and p) ----------------
__global__ __launch_bounds__(128) void k_backbone(
    const float* __restrict__ z,
    const float* __restrict__ sw1, const float* __restrict__ sb1,
    const float* __restrict__ sw2, const float* __restrict__ sb2,
    const float* __restrict__ pw1, const float* __restrict__ pb1,
    const float* __restrict__ pw2, const float* __restrict__ pb2,
    float* __restrict__ h2s, float* __restrict__ h2p)
{
  __shared__ float zsh[32];
  __shared__ float h1sh[2][64];
  const int b = blockIdx.x;
  const int tid = threadIdx.x;
  const int g = tid >> 6, o = tid & 63;
  if (tid < 32) zsh[tid] = z[b*32 + tid];
  __syncthreads();
  const float* w1 = g ? pw1 : sw1;
  const float* b1 = g ? pb1 : sb1;
  float acc = b1[o];
  #pragma unroll
  for (int i=0;i<32;i++) acc += zsh[i]*w1[i*64+o];
  h1sh[g][o] = reluf_(acc);
  __syncthreads();
  const float* w2 = g ? pw2 : sw2;
  const float* b2 = g ? pb2 : sb2;
  float acc2 = b2[o];
  #pragma unroll
  for (int i=0;i<64;i++) acc2 += h1sh[g][i]*w2[i*64+o];
  (g ? h2p : h2s)[b*64+o] = reluf_(acc2);
}

// ---------------- store helpers (fp32 / fp16 output) ----------------
__device__ __forceinline__ void store4v(float* p, const float4& v){
  *reinterpret_cast<float4*>(p) = v;
}
__device__ __forceinline__ void store4v(__half* p, const float4& v){
  reinterpret_cast<__half2*>(p)[0] = __floats2half2_rn(v.x, v.y);
  reinterpret_cast<__half2*>(p)[1] = __floats2half2_rn(v.z, v.w);
}

// ---------------- K2: register-blocked params GEMM, 4x b-tile reuse ----------------
// C[b,c] = sum_j h2[b,j]*w3[j,src(c)] + b3[src(c)]
// Tile: 128 c x (4 x 64 b); 256 threads = 8 ct x 32 bt; thread: 2 rows x 16 cols.
template <typename OT>
__global__ __launch_bounds__(256) void k_params4(
    const float* __restrict__ h2, const float* __restrict__ w3,
    const float* __restrict__ b3, OT* __restrict__ outp,
    int OC, int thr, int off, int stride)
{
  __shared__ float wt[64][132];   // [k][c] padded
  __shared__ float h2t[64][65];   // [b][k] padded
  __shared__ float bsh[128];
  const int c0 = blockIdx.x*128;
  const int tid = threadIdx.x;

  for (int idx = tid; idx < 8192; idx += 256){
    int j = idx >> 7, cc = idx & 127;
    int c = c0 + cc;
    int src = (c < thr) ? c : c + off;
    wt[j][cc] = (c < OC) ? w3[(size_t)j*stride + src] : 0.f;
  }
  if (tid < 128){
    int c = c0 + tid;
    int src = (c < thr) ? c : c + off;
    bsh[tid] = (c < OC) ? b3[src] : 0.f;
  }

  const int ct = tid & 7, bt = tid >> 3;
  for (int sub = 0; sub < 4; ++sub){
    const int b0 = blockIdx.y*256 + sub*64;
    __syncthreads();   // wt ready (sub=0) / previous h2t readers done (sub>0)
    for (int idx = tid; idx < 4096; idx += 256){
      int bb = idx >> 6, j = idx & 63;
      h2t[bb][j] = h2[(size_t)(b0+bb)*64 + j];
    }
    __syncthreads();

    float acc0[16], acc1[16];
    #pragma unroll
    for (int g=0; g<4; g++){
      #pragma unroll
      for (int e=0; e<4; e++){
        float bv = bsh[ct*4 + g*32 + e];
        acc0[g*4+e] = bv; acc1[g*4+e] = bv;
      }
    }
    #pragma unroll 4
    for (int k=0; k<64; k++){
      const float h0 = h2t[bt*2+0][k];
      const float h1 = h2t[bt*2+1][k];
      #pragma unroll
      for (int g=0; g<4; g++){
        const float4 wv = *reinterpret_cast<const float4*>(&wt[k][ct*4 + g*32]);
        acc0[g*4+0] += h0*wv.x; acc0[g*4+1] += h0*wv.y;
        acc0[g*4+2] += h0*wv.z; acc0[g*4+3] += h0*wv.w;
        acc1[g*4+0] += h1*wv.x; acc1[g*4+1] += h1*wv.y;
        acc1[g*4+2] += h1*wv.z; acc1[g*4+3] += h1*wv.w;
      }
    }
    #pragma unroll
    for (int g=0; g<4; g++){
      const int c = c0 + ct*4 + g*32;
      if (c < OC){
        const int br = b0 + bt*2;
        float4 s0 = make_float4(acc0[g*4+0],acc0[g*4+1],acc0[g*4+2],acc0[g*4+3]);
        float4 s1 = make_float4(acc1[g*4+0],acc1[g*4+1],acc1[g*4+2],acc1[g*4+3]);
        store4v(&outp[(size_t)br*OC + c], s0);
        store4v(&outp[(size_t)(br+1)*OC + c], s1);
      }
    }
  }
}

// ---------------- K3: 20 sequential hyper-GRU step pairs ----------------
// Register-resident weights, 4 barriers/substep.
// Net g = tid>>7 (0=s,1=p), lt = tid&127. Per net:
//   lanes 0-63 : e1 K-half psum (wA), gru-k col lt (wB), gru-rk col lt (wC)
//   lanes 64-95: e2 (wA), gru-k xh col (wB), gru-rk cand col (wC), gates+update
//   lanes 96-127: dec1 (wA); (p, lt<100) dec2 (wB)
__global__ __launch_bounds__(256, 3) void k_seq(
    const float* __restrict__ Ps, const float* __restrict__ Pp,
    float* __restrict__ Dout, float* __restrict__ Aout)
{
  __shared__ float xvT[64], xvI[64], initZ[64], hst[64];
  __shared__ float psA[128], e2s[64], gxs[128], ghs[128];
  __shared__ float rhs[64], d1s[32];

  const int b = blockIdx.x;
  const int tid = threadIdx.x;
  const int g = tid >> 7, lt = tid & 127;
  const float* Gp = g ? (Pp + (size_t)b*PP_COLS) : (Ps + (size_t)b*PS_COLS);
  const int rnn = g ? 4324 : 4192;

  float wA[32], wB[32], wC[32];
  float bA = 0.f, bB = 0.f;
  {
    int baseA;
    if (lt < 64)       baseA = (lt>>5)*1024 + (lt&31);     // enc1 (64x32), K-half
    else if (lt < 96)  baseA = 2080 + (lt-64);             // enc2 (32x32)
    else               baseA = 3136 + (lt-96);             // dec1 (32x32)
    #pragma unroll
    for (int i=0;i<32;i++) wA[i] = Gp[baseA + i*32];
    if (lt < 32)                  bA = Gp[2048 + lt];
    else if (lt >= 64 && lt < 96) bA = Gp[3104 + (lt-64)];
    else if (lt >= 96)            bA = Gp[4160 + (lt-96)];
    if (lt < 96){
      #pragma unroll
      for (int i=0;i<32;i++) wB[i] = Gp[rnn + i*96 + lt];
      bB = Gp[rnn + 6144 + lt];
      #pragma unroll
      for (int i=0;i<32;i++) wC[i] = Gp[rnn + 3072 + i*96 + lt];
    } else if (g == 1 && lt < 100){
      #pragma unroll
      for (int i=0;i<32;i++) wB[i] = Gp[4192 + i*4 + (lt-96)];
      bB = Gp[4320 + (lt-96)];
    }
  }

  if (tid < 64) hst[tid] = 0.f;
  if (tid < 32) initZ[tid] = Ps[(size_t)b*PS_COLS + 10432 + tid];
  else if (tid < 64) initZ[tid] = Pp[(size_t)b*PP_COLS + 10564 + (tid-32)];
  __syncthreads();
  if (tid < 64) xvT[tid] = initZ[tid];
  __syncthreads();

  auto substep = [&](const float* xv, int aidx, int t16, bool isTop){
    // A: e1 partial sums (lanes 0-63)
    if (lt < 64){
      float acc = (lt < 32) ? bA : 0.f;
      const int h32 = (lt >> 5) * 32;
      #pragma unroll
      for (int i=0;i<32;i++) acc += xv[h32+i]*wA[i];
      psA[g*64 + lt] = acc;
    }
    __syncthreads();
    // B: e2 = relu(e1) @ Wenc2 + b (lanes 64-95)
    if (lt >= 64 && lt < 96){
      float acc = bA;
      #pragma unroll
      for (int i=0;i<32;i++){
        float e1 = reluf_(psA[g*64+i] + psA[g*64+32+i]);
        acc += e1*wA[i];
      }
      e2s[g*32 + (lt-64)] = acc;
    }
    __syncthreads();
    // C: gx cols 0-63 + gh (lanes 0-63 -> LDS); xh cols 64-95 (lanes 64-95 -> reg)
    float xh = 0.f;
    if (lt < 64){
      float acc = bB, acc2 = 0.f;
      #pragma unroll
      for (int i=0;i<32;i++){
        float e2 = e2s[g*32+i];
        acc  += e2*wB[i];
        acc2 += hst[g*32+i]*wC[i];
      }
      gxs[g*64 + lt] = acc;
      ghs[g*64 + lt] = acc2;
    } else if (lt < 96){
      float acc = bB;
      #pragma unroll
      for (int i=0;i<32;i++) acc += e2s[g*32+i]*wB[i];
      xh = acc;
    }
    __syncthreads();
    // DEF: gates + candidate + h-update (lanes 64-95), then dec1/dec2 (lanes 96-127)
    // -- all producer/consumer pairs live in the same wave: LDS ordering, no barrier.
    if (lt >= 64 && lt < 96){
      int o = lt-64;
      float ho = hst[g*32+o];
      float zg = sigmoidf_(gxs[g*64+o]    + ghs[g*64+o]);
      float rg = sigmoidf_(gxs[g*64+32+o] + ghs[g*64+32+o]);
      rhs[g*32+o] = rg * ho;
      float acc = 0.f;
      #pragma unroll
      for (int i=0;i<32;i++) acc += rhs[g*32+i]*wC[i];
      float hh = tanhf(xh + acc);
      float hn = zg*ho + (1.f-zg)*hh;
      hst[g*32+o] = hn;
      if (isTop) xvT[g*32+o] = hn; else xvI[g*32+o] = hn;
    }
    if (isTop && tid < 64) xvI[tid] = initZ[tid];   // inner loop restarts from inits
    if (lt >= 96 && (g==1 || t16 >= 0)){
      int o = lt-96;
      float acc = bA;
      #pragma unroll
      for (int i=0;i<32;i++) acc += hst[g*32+i]*wA[i];
      float d = reluf_(acc);
      if (g == 0) Dout[((size_t)t16*BATCH + b)*32 + o] = d;
      else d1s[o] = d;
    }
    if (g == 1 && lt >= 96 && lt < 100){
      int o = lt-96;
      float acc = bB;
      #pragma unroll
      for (int i=0;i<32;i++) acc += d1s[i]*wB[i];
      Aout[((size_t)aidx*BATCH + b)*4 + o] = acc;
    }
    __syncthreads();
  };

  for (int t=0;t<4;t++){
    substep(xvT, t, -1, true);
    for (int k=0;k<4;k++){
      substep(xvI, 4 + t*4 + k, t*4 + k, false);
    }
  }
}

// ---------------- bilinear forward sampler (LDS image) ----------------
__device__ __forceinline__ float fetchpix(const float* __restrict__ img, int y, int x){
  if ((unsigned)y >= 28u || (unsigned)x >= 28u) return 0.0f;
  return img[y*28 + x];
}
__device__ __forceinline__ float bilin(const float* __restrict__ img,
                                       float a0, float a1, float a2, float a3,
                                       int r, int c){
  const float stepv = 2.0f/27.0f;
  float gxv = -1.0f + stepv*(float)c;
  float gyv = -1.0f + stepv*(float)r;
  float srcx = (a0 + 1.0f)*gxv + a2;
  float srcy = (a1 + 1.0f)*gyv + a3;
  float px = (srcx + 1.0f)*13.5f;
  float py = (srcy + 1.0f)*13.5f;
  float x0f = floorf(px), y0f = floorf(py);
  float wx = px - x0f, wy = py - y0f;
  int x0 = (int)x0f, y0 = (int)y0f;
  float v00 = fetchpix(img, y0,   x0);
  float v01 = fetchpix(img, y0,   x0+1);
  float v10 = fetchpix(img, y0+1, x0);
  float v11 = fetchpix(img, y0+1, x0+1);
  return v00*(1.0f-wx)*(1.0f-wy) + v01*wx*(1.0f-wy)
       + v10*(1.0f-wx)*wy + v11*wx*wy;
}

// ---------------- K4: fused decode: xhat (fp16 Pd stream) + both composites --------
__global__ __launch_bounds__(256) void k_dec(
    const __half* __restrict__ Pd, const float* __restrict__ Dm,
    const float* __restrict__ Am, float* __restrict__ outp)
{
  extern __shared__ float lds[];
  float* xh = lds;            // 16*784 = 12544
  float* o0 = lds + 12544;    // 4*784  = 3136
  float* Da = lds + 15680;    // 16*33  = 528
  float* av = lds + 16208;    // 80
  const int b = blockIdx.x;
  const int tid = threadIdx.x;

  for (int idx=tid; idx<512; idx+=256){
    int t = idx >> 5, i = idx & 31;
    Da[t*33 + i] = Dm[((size_t)t*BATCH + b)*32 + i];
  }
  if (tid < 16) Da[tid*33 + 32] = 1.0f;
  if (tid < 80) av[tid] = Am[((size_t)(tid>>2)*BATCH + b)*4 + (tid&3)];

  float4 acc4[16];
  #pragma unroll
  for (int t=0;t<16;t++) acc4[t] = make_float4(0.f,0.f,0.f,0.f);
  __syncthreads();

  const __half* Pdb = Pd + (size_t)b*PD_COLS;
  #pragma unroll 3
  for (int i=0;i<33;i++){
    const __half* row = Pdb + (i<32 ? i*784 : 25088);
    float4 v = make_float4(0.f,0.f,0.f,0.f);
    if (tid < 196){
      const __half2 h0 = reinterpret_cast<const __half2*>(row)[tid*2];
      const __half2 h1 = reinterpret_cast<const __half2*>(row)[tid*2+1];
      float2 f0 = __half22float2(h0), f1 = __half22float2(h1);
      v = make_float4(f0.x, f0.y, f1.x, f1.y);
    }
    #pragma unroll
    for (int t=0;t<16;t++){
      float da = Da[t*33 + i];
      acc4[t].x += da*v.x; acc4[t].y += da*v.y;
      acc4[t].z += da*v.z; acc4[t].w += da*v.w;
    }
  }
  if (tid < 196){
    #pragma unroll
    for (int t=0;t<16;t++)
      *reinterpret_cast<float4*>(&xh[t*784 + tid*4]) = acc4[t];
  }
  __syncthreads();

  // level-0 composite
  for (int idx=tid; idx<4*784; idx+=256){
    int t = idx / 784, pix = idx - t*784;
    int r = pix / 28, c = pix - r*28;
    float s = 0.f;
    #pragma unroll
    for (int k=0;k<4;k++){
      const float* ap = av + (4 + t*4 + k)*4;
      s += bilin(xh + (t*4+k)*784, ap[0], ap[1], ap[2], ap[3], r, c);
    }
    o0[t*784 + pix] = s;
  }
  __syncthreads();

  // level-1 composite -> d_out
  for (int idx=tid; idx<784; idx+=256){
    int r = idx / 28, c = idx - r*28;
    float s = 0.f;
    #pragma unroll
    for (int t=0;t<4;t++){
      const float* ap = av + t*4;
      s += bilin(o0 + t*784, ap[0], ap[1], ap[2], ap[3], r, c);
    }
    outp[(size_t)b*784 + idx] = s;
  }
}

extern "C" void kernel_launch(void* const* d_in, const int* in_sizes, int n_in,
                              void* d_out, int out_size, void* d_ws, size_t ws_size,
                              hipStream_t stream)
{
  const float* z   = (const float*)d_in[1];
  const float* sw1 = (const float*)d_in[2];
  const float* sb1 = (const float*)d_in[3];
  const float* sw2 = (const float*)d_in[4];
  const float* sb2 = (const float*)d_in[5];
  const float* sw3 = (const float*)d_in[6];
  const float* sb3 = (const float*)d_in[7];
  const float* pw1 = (const float*)d_in[8];
  const float* pb1 = (const float*)d_in[9];
  const float* pw2 = (const float*)d_in[10];
  const float* pb2 = (const float*)d_in[11];
  const float* pw3 = (const float*)d_in[12];
  const float* pb3 = (const float*)d_in[13];

  float* ws  = (float*)d_ws;
  float*  h2s = ws;                                  // 65536
  float*  h2p = ws + 65536;                          // 65536
  float*  Ps  = ws + 131072;                         // 1024*10464 f32
  float*  Pp  = ws + 131072 + 10715136;              // 1024*10596 f32
  // Pd (fp16) overlays Ps/Pp (dead after k_seq; stream-ordered)
  __half* Pd  = (__half*)(ws + 131072);              // 1024*25872 halfs (13.2M f32 slots)
  float*  Dm  = ws + 131072 + 10715136 + 10850304;   // 16*1024*32
  float*  Am  = Dm + 524288;                         // 20*1024*4
  float*  outp = (float*)d_out;

  (void)hipFuncSetAttribute(reinterpret_cast<const void*>(k_dec),
                            hipFuncAttributeMaxDynamicSharedMemorySize,
                            16288 * 4);

  hipLaunchKernelGGL(k_backbone, dim3(1024), dim3(128), 0, stream,
                     z, sw1,sb1,sw2,sb2, pw1,pb1,pw2,pb2, h2s, h2p);
  hipLaunchKernelGGL((k_params4<float>), dim3(82,4), dim3(256), 0, stream,
                     h2s, sw3, sb3, Ps, PS_COLS, 4192, 25872, SOUT);
  hipLaunchKernelGGL((k_params4<float>), dim3(83,4), dim3(256), 0, stream,
                     h2p, pw3, pb3, Pp, PP_COLS, 0x40000000, 0, POUT);
  hipLaunchKernelGGL(k_seq, dim3(1024), dim3(256), 0, stream,
                     Ps, Pp, Dm, Am);
  hipLaunchKernelGGL((k_params4<__half>), dim3(203,4), dim3(256), 0, stream,
                     h2s, sw3, sb3, Pd, PD_COLS, 0, 4192, SOUT);
  hipLaunchKernelGGL(k_dec, dim3(1024), dim3(256), 16288*4, stream,
                     Pd, Dm, Am, outp);
}